// Round 10
// baseline (203.385 us; speedup 1.0000x reference)
//
#include <hip/hip_runtime.h>

#define M 4096
#define L 32
#define K 64
#define NBLK 256
#define BLOCK 256
#define NPW 4                     // nodes per wave
#define MK (M * K)
#define FB 0xAAAAAAAAu            // ws poison; step tag = FB + s (s>=1)

// R10: wave-level self-timed dataflow. NO LDS staging, NO __syncthreads,
// NO device barrier of any kind.
//
// 1024 waves; wave w of block b owns nodes base..base+3 (base = 16b + 4w).
// Value exchange: 8-deep ring of tagged-u64 vectors in d_ws. v_s[node] is
// published as ONE aligned 8B sc1 store: (FB+s)<<32 | f32bits — tag visible
// <=> value visible. Consumers gather their 4x64 operands DIRECTLY from the
// ring (random 8B sc1 loads), verify the tag per lane, re-load only stale
// lanes (pure mall-RTT retries). The device pipelines: waves at different
// steps run concurrently; only true data dependencies serialize.
//
// Ring safety: overwrite needs lead >= 8 steps between two waves; a wave at
// step s has transitively verified its 3-hop predecessor closure at s-3,
// which for this K=64 random graph is ~the whole layer -> lead self-limits
// to ~3. Poison hi-word FB+0 never matches FB+s (s>=1) -> no memset.
//
// Step 1 computes v0 = relu(w_in*x + b_in) on the fly at the gathered
// indices (cached loads; inputs are ready at launch) -> no v0 exchange.
// vmcnt issue-order trick: tagged gathers issue BEFORE the next-layer
// fragment prefetch, so the first tag check waits only on the gathers;
// prefetch drains concurrently (max, not sum).
__global__ __launch_bounds__(BLOCK)
void net_kernel(const float* __restrict__ x,
                const float* __restrict__ w_in,
                const float* __restrict__ b_in,
                const float* __restrict__ w,
                const float* __restrict__ b,
                const int* __restrict__ igraf,
                float* __restrict__ out,
                unsigned long long* __restrict__ buf)   // 8 x M u64 ring
{
    const int tid  = threadIdx.x;
    const int blk  = blockIdx.x;
    const int wave = tid >> 6;
    const int lane = tid & 63;
    const int base = blk * 16 + wave * NPW;
    const bool finwave = (blk == NBLK - 1) && (wave == 3);  // owns node 4095

    // Fragments for step 1 (layer 0).
    float wv[NPW]; int iv[NPW]; float breg = 0.0f;
    {
        const size_t b0 = (size_t)base * K + (size_t)lane;
        #pragma unroll
        for (int j = 0; j < NPW; ++j) {
            wv[j] = w[b0 + (size_t)j * K];
            iv[j] = igraf[b0 + (size_t)j * K];
        }
        if (lane < NPW) breg = b[base + lane];
    }

    // ---- step 1: gather v0 operands on the fly (oldest in vmcnt queue) ----
    float gx[NPW], gw[NPW], gb[NPW];
    #pragma unroll
    for (int j = 0; j < NPW; ++j) {
        const int idx = iv[j];
        gw[j] = w_in[idx];
        gx[j] = x[idx];
        gb[j] = b_in[idx];
    }

    // Prefetch fragments for step 2 (layer 1) — drains during step-1 compute.
    float wn[NPW]; int in2[NPW]; float bn = 0.0f;
    {
        const size_t nb = (size_t)1 * MK + (size_t)base * K + (size_t)lane;
        #pragma unroll
        for (int j = 0; j < NPW; ++j) {
            wn[j]  = w[nb + (size_t)j * K];
            in2[j] = igraf[nb + (size_t)j * K];
        }
        if (lane < NPW) bn = b[1 * M + base + lane];
    }

    {
        float p[NPW];
        #pragma unroll
        for (int j = 0; j < NPW; ++j)
            p[j] = wv[j] * fmaxf(fmaf(gw[j], gx[j], gb[j]), 0.0f);
        #pragma unroll
        for (int j = 0; j < NPW; ++j) {
            #pragma unroll
            for (int off = 32; off > 0; off >>= 1)
                p[j] += __shfl_xor(p[j], off, 64);
        }
        float pj = p[0];
        pj = (lane == 1) ? p[1] : pj;
        pj = (lane == 2) ? p[2] : pj;
        pj = (lane == 3) ? p[3] : pj;
        const float val = 1.0f / (1.0f + __expf(-(pj + breg)));
        if (lane < NPW) {
            const unsigned long long pk =
                ((unsigned long long)(FB + 1u) << 32) |
                (unsigned long long)__float_as_uint(val);
            __hip_atomic_store(&buf[(size_t)1 * M + base + lane], pk,
                               __ATOMIC_RELAXED, __HIP_MEMORY_SCOPE_AGENT);
        }
        #pragma unroll
        for (int j = 0; j < NPW; ++j) { wv[j] = wn[j]; iv[j] = in2[j]; }
        breg = bn;
    }

    // ---- steps 2..32 ----
    for (int s = 2; s <= L; ++s) {
        const unsigned tag = FB + (unsigned)(s - 1);
        unsigned long long* src = buf + (size_t)((s - 1) & 7) * M;

        // Tagged gathers first (oldest): first tag check waits only these.
        unsigned long long g[NPW];
        #pragma unroll
        for (int j = 0; j < NPW; ++j)
            g[j] = __hip_atomic_load(&src[iv[j]], __ATOMIC_RELAXED,
                                     __HIP_MEMORY_SCOPE_AGENT);

        // Prefetch fragments for step s+1 (layer s); drains during tag-wait.
        if (s < L) {
            const size_t nb = (size_t)s * MK + (size_t)base * K + (size_t)lane;
            #pragma unroll
            for (int j = 0; j < NPW; ++j) {
                wn[j]  = w[nb + (size_t)j * K];
                in2[j] = igraf[nb + (size_t)j * K];
            }
            if (lane < NPW) bn = b[s * M + base + lane];
        }

        // Verify per-lane tags; re-load only stale lanes (pure RTT retries).
        for (;;) {
            bool ok = true;
            #pragma unroll
            for (int j = 0; j < NPW; ++j) {
                if ((unsigned)(g[j] >> 32) != tag) {
                    ok = false;
                    g[j] = __hip_atomic_load(&src[iv[j]], __ATOMIC_RELAXED,
                                             __HIP_MEMORY_SCOPE_AGENT);
                }
            }
            if (ok) break;
            __builtin_amdgcn_s_sleep(1);
        }

        float p[NPW];
        #pragma unroll
        for (int j = 0; j < NPW; ++j)
            p[j] = wv[j] * __uint_as_float((unsigned)g[j]);
        #pragma unroll
        for (int j = 0; j < NPW; ++j) {
            #pragma unroll
            for (int off = 32; off > 0; off >>= 1)
                p[j] += __shfl_xor(p[j], off, 64);
        }
        float pj = p[0];
        pj = (lane == 1) ? p[1] : pj;
        pj = (lane == 2) ? p[2] : pj;
        pj = (lane == 3) ? p[3] : pj;
        const float val = 1.0f / (1.0f + __expf(-(pj + breg)));

        if (s == L) {   // only finwave reaches s == L
            if (lane == 3) out[0] = val;   // node 4095 = base+3, lane 3
            break;
        }

        if (lane < NPW) {
            const unsigned long long pk =
                ((unsigned long long)(FB + (unsigned)s) << 32) |
                (unsigned long long)__float_as_uint(val);
            __hip_atomic_store(&buf[(size_t)(s & 7) * M + base + lane], pk,
                               __ATOMIC_RELAXED, __HIP_MEMORY_SCOPE_AGENT);
        }

        if (s == L - 1 && !finwave) return;  // published v31; only finwave goes on

        #pragma unroll
        for (int j = 0; j < NPW; ++j) { wv[j] = wn[j]; iv[j] = in2[j]; }
        breg = bn;
    }
}

extern "C" void kernel_launch(void* const* d_in, const int* in_sizes, int n_in,
                              void* d_out, int out_size, void* d_ws, size_t ws_size,
                              hipStream_t stream) {
    const float* x     = (const float*)d_in[0];
    const float* w_in  = (const float*)d_in[1];
    const float* b_in  = (const float*)d_in[2];
    const float* wt    = (const float*)d_in[3];
    const float* b     = (const float*)d_in[4];
    const int*   igraf = (const int*)d_in[5];
    float*       out   = (float*)d_out;

    unsigned long long* buf = (unsigned long long*)d_ws;   // 8 x M x 8B = 256KB

    // No memset: poison hi-word = FB+0 never matches a step tag (FB+s, s>=1).
    hipLaunchKernelGGL(net_kernel, dim3(NBLK), dim3(BLOCK), 0, stream,
                       x, w_in, b_in, wt, b, igraf, out, buf);
    (void)in_sizes; (void)n_in; (void)out_size; (void)ws_size;
}